// Round 1
// baseline (242.749 us; speedup 1.0000x reference)
//
#include <hip/hip_runtime.h>
#include <hip/hip_bf16.h>
#include <math.h>

// KoLeo loss, MI355X. Fused normalize -> bf16 fragment repack -> MFMA gram
// row-max (never materializes the 16384^2 gram) -> log/mean epilogue.
//
// F layout: chunk(it,ks,lane) = (it*8+ks)*64 + lane, each chunk = 16B = 8 bf16
//   holding xn[it*16 + (lane&15)][ks*32 + (lane>>4)*8 .. +7].
// This IS the mfma_f32_16x16x32_bf16 A/B fragment layout, so operand loads
// are 1024B fully-coalesced dwordx4 per wave.

typedef __attribute__((ext_vector_type(8))) short bf16x8;   // 8 bf16 = 4 VGPR
typedef __attribute__((ext_vector_type(4))) float f32x4;

#define NROWS 16384
#define NDIM  256

// ---------------- K0: row 1/norm ----------------
__global__ __launch_bounds__(256) void knorm(const float* __restrict__ x,
                                             float* __restrict__ rn) {
    int wid = threadIdx.x >> 6, lane = threadIdx.x & 63;
    int row = blockIdx.x * 4 + wid;                 // 4096 blocks * 4 waves
    const float4* xr = (const float4*)(x + (size_t)row * NDIM);
    float4 v = xr[lane];                            // 64 lanes * 4 f32 = 256
    float ss = v.x * v.x + v.y * v.y + v.z * v.z + v.w * v.w;
    #pragma unroll
    for (int m = 1; m < 64; m <<= 1) ss += __shfl_xor(ss, m, 64);
    if (lane == 0) rn[row] = 1.0f / fmaxf(sqrtf(ss), 1e-12f);
}

// ---------------- K1: normalize + pack to fragment layout ----------------
__device__ inline unsigned bf_rne(float f) {
    union { float f; unsigned u; } c; c.f = f;
    return (c.u + 0x7FFFu + ((c.u >> 16) & 1u)) >> 16;
}
__device__ inline unsigned pack2(float lo, float hi) {
    return bf_rne(lo) | (bf_rne(hi) << 16);
}

__global__ __launch_bounds__(256) void kpack(const float* __restrict__ x,
                                             const float* __restrict__ rn,
                                             uint4* __restrict__ F) {
    int g = blockIdx.x * 256 + threadIdx.x;         // chunk id, 524288 total
    int jt   = g >> 9;                              // 512 chunks per 16-row tile
    int rem  = g & 511;
    int ks   = rem >> 6;
    int lane = rem & 63;
    int row  = jt * 16 + (lane & 15);
    int kb   = ks * 32 + (lane >> 4) * 8;
    float s = rn[row];
    const float4* xr = (const float4*)(x + (size_t)row * NDIM + kb);
    float4 a = xr[0], b = xr[1];
    uint4 o;
    o.x = pack2(a.x * s, a.y * s);
    o.y = pack2(a.z * s, a.w * s);
    o.z = pack2(b.x * s, b.y * s);
    o.w = pack2(b.z * s, b.w * s);
    F[g] = o;                                       // fully coalesced 16B
}

// ---------------- K2: fused gram + row-max ----------------
// 256 blocks (one per 64 i-rows) x 512 threads (8 waves, 2/SIMD).
// Wave holds all 64 i-rows' fragments in regs (4 tiles x 8 ksteps x 4 VGPR),
// streams its 1/8th of the j-range, 32 MFMAs per 16-j tile.
__global__ __launch_bounds__(512, 2) void kmax(const bf16x8* __restrict__ Fv,
                                               float* __restrict__ rowmax) {
    const int tid  = threadIdx.x;
    const int wid  = tid >> 6;
    const int lane = tid & 63;
    const int i0   = blockIdx.x * 64;

    bf16x8 bfr[4][8];
    #pragma unroll
    for (int t = 0; t < 4; ++t) {
        #pragma unroll
        for (int ks = 0; ks < 8; ++ks)
            bfr[t][ks] = Fv[((i0 >> 4) + t) * 512 + ks * 64 + lane];
    }

    float rmax[4] = {-1e30f, -1e30f, -1e30f, -1e30f};
    // diag element (j==i) sits at reg r == dlane, independent of jt
    const int dlane = (lane & 15) - ((lane >> 4) << 2);

    const int jt_beg = wid * 128, jt_end = jt_beg + 128;
    for (int jt = jt_beg; jt < jt_end; ++jt) {
        bf16x8 af[8];
        const bf16x8* base = Fv + jt * 512 + lane;
        #pragma unroll
        for (int ks = 0; ks < 8; ++ks) af[ks] = base[ks * 64];

        f32x4 acc[4];
        #pragma unroll
        for (int t = 0; t < 4; ++t) {
            f32x4 c = {0.f, 0.f, 0.f, 0.f};
            #pragma unroll
            for (int ks = 0; ks < 8; ++ks)
                c = __builtin_amdgcn_mfma_f32_16x16x32_bf16(af[ks], bfr[t][ks],
                                                            c, 0, 0, 0);
            acc[t] = c;   // D[n=lane&15 -> i, m=(lane>>4)*4+reg -> j]
        }

        unsigned dd = (unsigned)(jt * 16 - i0);
        if (dd < 64u) {                    // j-tile overlaps block's i-rows
            int td = (int)(dd >> 4);
            #pragma unroll
            for (int t = 0; t < 4; ++t) {
                #pragma unroll
                for (int r = 0; r < 4; ++r) {
                    float v = acc[t][r];
                    if (t == td && r == dlane) v = -1e30f;   // mask diagonal
                    rmax[t] = fmaxf(rmax[t], v);
                }
            }
        } else {
            #pragma unroll
            for (int t = 0; t < 4; ++t)
                rmax[t] = fmaxf(rmax[t],
                                fmaxf(fmaxf(acc[t][0], acc[t][1]),
                                      fmaxf(acc[t][2], acc[t][3])));
        }
    }

    // lanes {l, l^16, l^32, l^48} share the same i = i0 + t*16 + (l&15)
    #pragma unroll
    for (int t = 0; t < 4; ++t) {
        rmax[t] = fmaxf(rmax[t], __shfl_xor(rmax[t], 16, 64));
        rmax[t] = fmaxf(rmax[t], __shfl_xor(rmax[t], 32, 64));
    }

    __shared__ float part[8][64];
    if (lane < 16) {
        #pragma unroll
        for (int t = 0; t < 4; ++t) part[wid][t * 16 + lane] = rmax[t];
    }
    __syncthreads();
    if (tid < 64) {
        float m = part[0][tid];
        #pragma unroll
        for (int w = 1; w < 8; ++w) m = fmaxf(m, part[w][tid]);
        rowmax[i0 + tid] = m;
    }
}

// ---------------- K3: loss epilogue ----------------
__global__ __launch_bounds__(1024) void kloss(const float* __restrict__ rowmax,
                                              float* __restrict__ out) {
    float acc = 0.f;
    for (int i = threadIdx.x; i < NROWS; i += 1024) {
        float g = rowmax[i];
        float d = sqrtf(fmaxf(2.f - 2.f * g, 0.f));
        acc += logf(d + 1e-8f);
    }
    #pragma unroll
    for (int m = 1; m < 64; m <<= 1) acc += __shfl_xor(acc, m, 64);
    __shared__ float p[16];
    int wid = threadIdx.x >> 6, lane = threadIdx.x & 63;
    if (lane == 0) p[wid] = acc;
    __syncthreads();
    if (threadIdx.x == 0) {
        float s = 0.f;
        #pragma unroll
        for (int w = 0; w < 16; ++w) s += p[w];
        out[0] = -s / (float)NROWS;
    }
}

extern "C" void kernel_launch(void* const* d_in, const int* in_sizes, int n_in,
                              void* d_out, int out_size, void* d_ws, size_t ws_size,
                              hipStream_t stream) {
    const float* x = (const float*)d_in[0];
    float* out = (float*)d_out;
    char* ws = (char*)d_ws;

    uint4* F       = (uint4*)ws;                              // 8 MiB
    float* rn      = (float*)(ws + 8u * 1024u * 1024u);       // 64 KiB
    float* rowmax  = (float*)(ws + 8u * 1024u * 1024u + 65536u); // 64 KiB

    knorm<<<NROWS / 4, 256, 0, stream>>>(x, rn);
    kpack<<<(NROWS * NDIM / 8) / 256, 256, 0, stream>>>(x, rn, F);
    kmax <<<NROWS / 64, 512, 0, stream>>>((const bf16x8*)F, rowmax);
    kloss<<<1, 1024, 0, stream>>>(rowmax, out);
}

// Round 2
// 133.337 us; speedup vs baseline: 1.8206x; 1.8206x over previous
//
#include <hip/hip_runtime.h>
#include <hip/hip_bf16.h>
#include <math.h>

// KoLeo loss, MI355X. Fused normalize -> bf16 fragment repack -> MFMA gram
// row-max (never materializes the 16384^2 gram) -> log/mean epilogue.
//
// F layout: chunk(it,ks,lane) = (it*8+ks)*64 + lane, each chunk = 16B = 8 bf16
//   holding xn[it*16 + (lane&15)][ks*32 + (lane>>4)*8 .. +7].
// This IS the mfma_f32_16x16x32_bf16 A/B fragment layout, so operand loads /
// LDS staging are fully-coalesced linear 16B-per-lane transfers.
//
// kmax v2: block = 8 waves x 32 i-rows = 256 i-rows, j split 8 ways
// (js = blockIdx&7 -> XCD-aligned so each XCD L2 re-serves one 2MB j-slice).
// j-tiles staged into double-buffered LDS via global_load_lds(16B), shared by
// all 8 waves; i-fragments held in regs (64 VGPR). 2-phase pipeline.

typedef __attribute__((ext_vector_type(8))) short bf16x8;   // 8 bf16 = 4 VGPR
typedef __attribute__((ext_vector_type(4))) float f32x4;

#define NROWS 16384
#define NDIM  256
#define JSPLIT 8
#define JT_PER (NROWS / 16 / JSPLIT)   // 128 j-tiles per block

// ---------------- K0: row 1/norm ----------------
__global__ __launch_bounds__(256) void knorm(const float* __restrict__ x,
                                             float* __restrict__ rn) {
    int wid = threadIdx.x >> 6, lane = threadIdx.x & 63;
    int row = blockIdx.x * 4 + wid;                 // 4096 blocks * 4 waves
    const float4* xr = (const float4*)(x + (size_t)row * NDIM);
    float4 v = xr[lane];                            // 64 lanes * 4 f32 = 256
    float ss = v.x * v.x + v.y * v.y + v.z * v.z + v.w * v.w;
    #pragma unroll
    for (int m = 1; m < 64; m <<= 1) ss += __shfl_xor(ss, m, 64);
    if (lane == 0) rn[row] = 1.0f / fmaxf(sqrtf(ss), 1e-12f);
}

// ---------------- K1: normalize + pack to fragment layout ----------------
__device__ inline unsigned bf_rne(float f) {
    union { float f; unsigned u; } c; c.f = f;
    return (c.u + 0x7FFFu + ((c.u >> 16) & 1u)) >> 16;
}
__device__ inline unsigned pack2(float lo, float hi) {
    return bf_rne(lo) | (bf_rne(hi) << 16);
}

__global__ __launch_bounds__(256) void kpack(const float* __restrict__ x,
                                             const float* __restrict__ rn,
                                             uint4* __restrict__ F) {
    int g = blockIdx.x * 256 + threadIdx.x;         // chunk id, 524288 total
    int jt   = g >> 9;                              // 512 chunks per 16-row tile
    int rem  = g & 511;
    int ks   = rem >> 6;
    int lane = rem & 63;
    int row  = jt * 16 + (lane & 15);
    int kb   = ks * 32 + (lane >> 4) * 8;
    float s = rn[row];
    const float4* xr = (const float4*)(x + (size_t)row * NDIM + kb);
    float4 a = xr[0], b = xr[1];
    uint4 o;
    o.x = pack2(a.x * s, a.y * s);
    o.y = pack2(a.z * s, a.w * s);
    o.z = pack2(b.x * s, b.y * s);
    o.w = pack2(b.z * s, b.w * s);
    F[g] = o;                                       // fully coalesced 16B
}

// ---------------- K2: fused gram + row-max (LDS-shared j-stream) ----------
__device__ inline void stage16(const uint4* __restrict__ g, const uint4* l) {
    __builtin_amdgcn_global_load_lds(
        (const __attribute__((address_space(1))) unsigned*)g,
        (__attribute__((address_space(3))) unsigned*)l, 16, 0, 0);
}

__global__ __launch_bounds__(512, 4) void kmax(const uint4* __restrict__ F,
                                               float* __restrict__ part) {
    __shared__ uint4 sbuf[2][512];                  // 2 x 8KB j-tile buffers

    const int tid  = threadIdx.x;
    const int wid  = tid >> 6;
    const int lane = tid & 63;
    const int ib   = blockIdx.x >> 3;               // i-block (256 rows)
    const int js   = blockIdx.x & 7;                // j-slice (XCD-aligned)
    const int i0w  = ib * 256 + wid * 32;           // wave's first i-row
    const int itb  = ib * 16 + wid * 2;             // wave's first 16-row i-tile

    // hoist i-side fragments: 2 tiles x 8 ksteps x 4 VGPR = 64 VGPR
    bf16x8 bfr0[8], bfr1[8];
    #pragma unroll
    for (int ks = 0; ks < 8; ++ks) {
        bfr0[ks] = ((const bf16x8*)F)[(itb + 0) * 512 + ks * 64 + lane];
        bfr1[ks] = ((const bf16x8*)F)[(itb + 1) * 512 + ks * 64 + lane];
    }

    const int jt0 = js * JT_PER;                    // global first j-tile
    // prologue: stage tile jt0 into buf 0 (linear: thread tid -> chunk tid)
    stage16(F + (size_t)jt0 * 512 + tid, &sbuf[0][wid * 64]);
    __syncthreads();

    float rmax0 = -1e30f, rmax1 = -1e30f;
    const int dlane = (lane & 15) - ((lane >> 4) << 2);  // diag reg idx (or OOB)

    int cur = 0;
    for (int jt = 0; jt < JT_PER; ++jt) {
        if (jt + 1 < JT_PER)                        // stage next tile
            stage16(F + (size_t)(jt0 + jt + 1) * 512 + tid,
                    &sbuf[cur ^ 1][wid * 64]);

        f32x4 c0 = {0.f, 0.f, 0.f, 0.f}, c1 = {0.f, 0.f, 0.f, 0.f};
        #pragma unroll
        for (int ks = 0; ks < 8; ++ks) {
            bf16x8 af = *(const bf16x8*)&sbuf[cur][ks * 64 + lane];
            c0 = __builtin_amdgcn_mfma_f32_16x16x32_bf16(af, bfr0[ks], c0, 0, 0, 0);
            c1 = __builtin_amdgcn_mfma_f32_16x16x32_bf16(af, bfr1[ks], c1, 0, 0, 0);
        }

        unsigned dd = (unsigned)((jt0 + jt) * 16 - i0w);
        if (dd < 32u) {                             // j-tile hits wave's i-rows
            int td = (int)(dd >> 4);
            #pragma unroll
            for (int r = 0; r < 4; ++r) {
                float v0 = c0[r], v1 = c1[r];
                if (td == 0 && r == dlane) v0 = -1e30f;
                if (td == 1 && r == dlane) v1 = -1e30f;
                rmax0 = fmaxf(rmax0, v0);
                rmax1 = fmaxf(rmax1, v1);
            }
        } else {
            rmax0 = fmaxf(rmax0, fmaxf(fmaxf(c0[0], c0[1]), fmaxf(c0[2], c0[3])));
            rmax1 = fmaxf(rmax1, fmaxf(fmaxf(c1[0], c1[1]), fmaxf(c1[2], c1[3])));
        }

        __syncthreads();                            // drains stage vmcnt too
        cur ^= 1;
    }

    // lanes {l, l^16, l^32, l^48} share i = i0w + t*16 + (l&15)
    rmax0 = fmaxf(rmax0, __shfl_xor(rmax0, 16, 64));
    rmax0 = fmaxf(rmax0, __shfl_xor(rmax0, 32, 64));
    rmax1 = fmaxf(rmax1, __shfl_xor(rmax1, 16, 64));
    rmax1 = fmaxf(rmax1, __shfl_xor(rmax1, 32, 64));
    if (lane < 16) {
        part[(size_t)js * NROWS + i0w + lane]      = rmax0;
        part[(size_t)js * NROWS + i0w + 16 + lane] = rmax1;
    }
}

// ---------------- K3: loss epilogue (combine j-slice partials) ------------
__global__ __launch_bounds__(1024) void kloss(const float* __restrict__ part,
                                              float* __restrict__ out) {
    float acc = 0.f;
    for (int i = threadIdx.x; i < NROWS; i += 1024) {
        float g = part[i];
        #pragma unroll
        for (int p = 1; p < JSPLIT; ++p) g = fmaxf(g, part[p * NROWS + i]);
        float d = sqrtf(fmaxf(2.f - 2.f * g, 0.f));
        acc += logf(d + 1e-8f);
    }
    #pragma unroll
    for (int m = 1; m < 64; m <<= 1) acc += __shfl_xor(acc, m, 64);
    __shared__ float p[16];
    int wid = threadIdx.x >> 6, lane = threadIdx.x & 63;
    if (lane == 0) p[wid] = acc;
    __syncthreads();
    if (threadIdx.x == 0) {
        float s = 0.f;
        #pragma unroll
        for (int w = 0; w < 16; ++w) s += p[w];
        out[0] = -s / (float)NROWS;
    }
}

extern "C" void kernel_launch(void* const* d_in, const int* in_sizes, int n_in,
                              void* d_out, int out_size, void* d_ws, size_t ws_size,
                              hipStream_t stream) {
    const float* x = (const float*)d_in[0];
    float* out = (float*)d_out;
    char* ws = (char*)d_ws;

    uint4* F     = (uint4*)ws;                                  // 8 MiB
    float* rn    = (float*)(ws + 8u * 1024u * 1024u);           // 64 KiB
    float* part  = (float*)(ws + 8u * 1024u * 1024u + 65536u);  // 512 KiB

    knorm<<<NROWS / 4, 256, 0, stream>>>(x, rn);
    kpack<<<(NROWS * NDIM / 8) / 256, 256, 0, stream>>>(x, rn, F);
    kmax <<<(NROWS / 256) * JSPLIT, 512, 0, stream>>>(F, part);
    kloss<<<1, 1024, 0, stream>>>(part, out);
}

// Round 3
// 128.433 us; speedup vs baseline: 1.8901x; 1.0382x over previous
//
#include <hip/hip_runtime.h>
#include <hip/hip_bf16.h>
#include <math.h>

// KoLeo loss, MI355X. Fused normalize -> bf16 fragment repack -> MFMA gram
// row-max (never materializes the 16384^2 gram) -> log/mean epilogue.
//
// v3: 32x32x16 MFMA, 64 i-rows/wave (halves LDS bytes/FLOP vs v2 -> MFMA-bound).
//
// F layout (32-row tiles): chunk(t32,ks,lane) = t32*1024 + ks*64 + lane,
//   16B chunk = 8 bf16 of xn[t32*32 + (lane&31)][ks*16 + (lane>>5)*8 .. +7].
// This IS the mfma_f32_32x32x16_bf16 A/B fragment layout, so operand loads /
// LDS staging are fully-coalesced linear 16B-per-lane transfers.

typedef __attribute__((ext_vector_type(8))) short bf16x8;    // 8 bf16 = 4 VGPR
typedef __attribute__((ext_vector_type(16))) float f32x16;   // 32x32 acc

#define NROWS 16384
#define NDIM  256
#define JSPLIT 8
#define JT32_PER (NROWS / 32 / JSPLIT)   // 64 j-tiles (32 rows) per block

// ---------------- K0: row 1/norm ----------------
__global__ __launch_bounds__(256) void knorm(const float* __restrict__ x,
                                             float* __restrict__ rn) {
    int wid = threadIdx.x >> 6, lane = threadIdx.x & 63;
    int row = blockIdx.x * 4 + wid;                 // 4096 blocks * 4 waves
    const float4* xr = (const float4*)(x + (size_t)row * NDIM);
    float4 v = xr[lane];                            // 64 lanes * 4 f32 = 256
    float ss = v.x * v.x + v.y * v.y + v.z * v.z + v.w * v.w;
    #pragma unroll
    for (int m = 1; m < 64; m <<= 1) ss += __shfl_xor(ss, m, 64);
    if (lane == 0) rn[row] = 1.0f / fmaxf(sqrtf(ss), 1e-12f);
}

// ---------------- K1: normalize + pack to 32x32 fragment layout -----------
__device__ inline unsigned bf_rne(float f) {
    union { float f; unsigned u; } c; c.f = f;
    return (c.u + 0x7FFFu + ((c.u >> 16) & 1u)) >> 16;
}
__device__ inline unsigned pack2(float lo, float hi) {
    return bf_rne(lo) | (bf_rne(hi) << 16);
}

__global__ __launch_bounds__(256) void kpack(const float* __restrict__ x,
                                             const float* __restrict__ rn,
                                             uint4* __restrict__ F) {
    int g = blockIdx.x * 256 + threadIdx.x;         // chunk id, 524288 total
    int t32  = g >> 10;                             // 1024 chunks per 32-row tile
    int rem  = g & 1023;
    int ks   = rem >> 6;                            // 16 k-steps of 16
    int lane = rem & 63;
    int row  = t32 * 32 + (lane & 31);
    int kb   = ks * 16 + (lane >> 5) * 8;
    float s = rn[row];
    const float4* xr = (const float4*)(x + (size_t)row * NDIM + kb);
    float4 a = xr[0], b = xr[1];
    uint4 o;
    o.x = pack2(a.x * s, a.y * s);
    o.y = pack2(a.z * s, a.w * s);
    o.z = pack2(b.x * s, b.y * s);
    o.w = pack2(b.z * s, b.w * s);
    F[g] = o;                                       // fully coalesced 16B
}

// ---------------- K2: fused gram + row-max (LDS-shared j-stream) ----------
__device__ inline void stage16(const uint4* __restrict__ g, const uint4* l) {
    __builtin_amdgcn_global_load_lds(
        (const __attribute__((address_space(1))) unsigned*)g,
        (__attribute__((address_space(3))) unsigned*)l, 16, 0, 0);
}

// 256 blocks (32 i-blocks x 8 j-slices), 512 threads = 8 waves.
// Wave holds 2 x 32-row i-tiles in regs (128 VGPR), streams 32-row j-tiles
// through double-buffered LDS (2 x 16KB), 32 MFMA per tile per wave.
__global__ __launch_bounds__(512, 2) void kmax(const uint4* __restrict__ F,
                                               float* __restrict__ part) {
    __shared__ uint4 sbuf[2][1024];                 // 2 x 16KB j-tile buffers

    const int tid  = threadIdx.x;
    const int wid  = tid >> 6;
    const int lane = tid & 63;
    const int ib   = blockIdx.x >> 3;               // i-block (512 rows)
    const int js   = blockIdx.x & 7;                // j-slice (XCD-aligned)
    const int i0w  = ib * 512 + wid * 64;           // wave's first i-row
    const int itb  = ib * 16 + wid * 2;             // wave's first 32-row i-tile

    // hoist i-side fragments: 2 tiles x 16 ksteps x 4 VGPR = 128 VGPR
    bf16x8 bfr0[16], bfr1[16];
    #pragma unroll
    for (int ks = 0; ks < 16; ++ks) {
        bfr0[ks] = ((const bf16x8*)F)[(itb + 0) * 1024 + ks * 64 + lane];
        bfr1[ks] = ((const bf16x8*)F)[(itb + 1) * 1024 + ks * 64 + lane];
    }

    const int jt0 = js * JT32_PER;                  // global first j-tile
    // prologue: stage tile jt0 into buf 0 (linear: thread t -> chunk t)
    stage16(F + (size_t)jt0 * 1024 + tid,       &sbuf[0][wid * 64]);
    stage16(F + (size_t)jt0 * 1024 + 512 + tid, &sbuf[0][512 + wid * 64]);
    __syncthreads();

    float rmax0 = -1e30f, rmax1 = -1e30f;
    // diagonal: i_local = lane&31 (col); j_local = (r&3)+8*(r>>2)+4*(lane>>5)
    const int L  = lane & 31, hi = lane >> 5;
    const bool dvalid = (((L >> 2) & 1) == hi);
    const int  dreg   = (L & 3) | ((L >> 3) << 2);

    int cur = 0;
    for (int jt = 0; jt < JT32_PER; ++jt) {
        if (jt + 1 < JT32_PER) {                    // stage next tile
            const uint4* gp = F + (size_t)(jt0 + jt + 1) * 1024;
            stage16(gp + tid,       &sbuf[cur ^ 1][wid * 64]);
            stage16(gp + 512 + tid, &sbuf[cur ^ 1][512 + wid * 64]);
        }

        f32x16 c0 = {0.f}, c1 = {0.f};
        #pragma unroll
        for (int ks = 0; ks < 16; ++ks) {
            bf16x8 af = *(const bf16x8*)&sbuf[cur][ks * 64 + lane];
            c0 = __builtin_amdgcn_mfma_f32_32x32x16_bf16(af, bfr0[ks], c0, 0, 0, 0);
            c1 = __builtin_amdgcn_mfma_f32_32x32x16_bf16(af, bfr1[ks], c1, 0, 0, 0);
        }

        unsigned dd = (unsigned)((jt0 + jt) * 32 - i0w);
        if (dd < 64u) {                             // j-tile hits wave's i-rows
            int td = (int)(dd >> 5);
            #pragma unroll
            for (int r = 0; r < 16; ++r) {
                float v0 = c0[r], v1 = c1[r];
                if (td == 0 && dvalid && r == dreg) v0 = -1e30f;
                if (td == 1 && dvalid && r == dreg) v1 = -1e30f;
                rmax0 = fmaxf(rmax0, v0);
                rmax1 = fmaxf(rmax1, v1);
            }
        } else {
            #pragma unroll
            for (int r = 0; r < 16; ++r) {
                rmax0 = fmaxf(rmax0, c0[r]);
                rmax1 = fmaxf(rmax1, c1[r]);
            }
        }

        __syncthreads();                            // drains stage vmcnt too
        cur ^= 1;
    }

    // lanes l and l^32 share the same i-col; combine then write from lane<32
    rmax0 = fmaxf(rmax0, __shfl_xor(rmax0, 32, 64));
    rmax1 = fmaxf(rmax1, __shfl_xor(rmax1, 32, 64));
    if (lane < 32) {
        part[(size_t)js * NROWS + i0w + L]      = rmax0;
        part[(size_t)js * NROWS + i0w + 32 + L] = rmax1;
    }
}

// ---------------- K3: loss epilogue (combine j-slice partials) ------------
__global__ __launch_bounds__(1024) void kloss(const float* __restrict__ part,
                                              float* __restrict__ out) {
    float acc = 0.f;
    for (int i = threadIdx.x; i < NROWS; i += 1024) {
        float g = part[i];
        #pragma unroll
        for (int p = 1; p < JSPLIT; ++p) g = fmaxf(g, part[p * NROWS + i]);
        float d = sqrtf(fmaxf(2.f - 2.f * g, 0.f));
        acc += logf(d + 1e-8f);
    }
    #pragma unroll
    for (int m = 1; m < 64; m <<= 1) acc += __shfl_xor(acc, m, 64);
    __shared__ float p[16];
    int wid = threadIdx.x >> 6, lane = threadIdx.x & 63;
    if (lane == 0) p[wid] = acc;
    __syncthreads();
    if (threadIdx.x == 0) {
        float s = 0.f;
        #pragma unroll
        for (int w = 0; w < 16; ++w) s += p[w];
        out[0] = -s / (float)NROWS;
    }
}

extern "C" void kernel_launch(void* const* d_in, const int* in_sizes, int n_in,
                              void* d_out, int out_size, void* d_ws, size_t ws_size,
                              hipStream_t stream) {
    const float* x = (const float*)d_in[0];
    float* out = (float*)d_out;
    char* ws = (char*)d_ws;

    uint4* F     = (uint4*)ws;                                  // 8 MiB
    float* rn    = (float*)(ws + 8u * 1024u * 1024u);           // 64 KiB
    float* part  = (float*)(ws + 8u * 1024u * 1024u + 65536u);  // 512 KiB

    knorm<<<NROWS / 4, 256, 0, stream>>>(x, rn);
    kpack<<<(NROWS * NDIM / 8) / 256, 256, 0, stream>>>(x, rn, F);
    kmax <<<(NROWS / 512) * JSPLIT, 512, 0, stream>>>(F, part);
    kloss<<<1, 1024, 0, stream>>>(part, out);
}